// Round 1
// baseline (518.203 us; speedup 1.0000x reference)
//
#include <hip/hip_runtime.h>
#include <hip/hip_bf16.h>
#include <stdint.h>
#include <stddef.h>

// Problem constants (match reference)
#define NB 16       // genes
#define NS 4096     // splice sites per gene
#define NSA 4098    // augmented sites (incl. gene_start, gene_end)
#define NC 512      // channels per site rep
#define NJ 4096     // junctions per gene
#define NT 64       // transcripts per gene
#define NKJ 32      // junctions per transcript
#define KD 1024     // 2*NC = MLP in/hidden dim
#define NM (NB * NJ)  // 65536 rows

// prep kernel block ranges
#define PREP_W_BLKS 2048                    // weight transpose tiles
#define PREP_AUG_BLKS ((NB * NSA) / 4)      // 16392: aug rows / 4
#define PREP_POT_BLKS 64                    // pot zeroing

typedef __hip_bfloat16 bf16;
typedef __attribute__((ext_vector_type(8))) short bf16x8;  // 8 bf16 = 4 VGPRs
typedef __attribute__((ext_vector_type(4))) float f32x4;

// ---------------------------------------------------------------------------
// 8-phase 256x256 GEMM (HK-style schedule in plain HIP).
// BM=BN=256, BK=64, 8 waves (2M x 4N), per-wave C = 128x64 (acc 8x4 f32x4).
// LDS 128 KiB: A[2][256][64] + B[2][256][64] bf16, double-buffered K-tiles.
// Swizzle: logical (row, 16B-granule g) stored at slot g ^ (row&7); LDS dest
// of global_load_lds stays linear, the global SOURCE is pre-swizzled
// (both-sides rule). ds_read applies the same XOR -> conflict-free (measured
// 0 conflicts with this scheme at 128 tile).
// Counted vmcnt: only vmcnt(4) at phases 4 and 8 (2 half-tiles in flight
// across barriers); never drained to 0 inside the loop except last iter P4.

__device__ __forceinline__ void gload_lds16(const bf16* g, bf16* l) {
  __builtin_amdgcn_global_load_lds(
      (const __attribute__((address_space(1))) void*)g,
      (__attribute__((address_space(3))) void*)l, 16, 0, 0);
}

#define A_BUF(b) (smem + (b) * 32768)
#define B_BUF(b) (smem + 65536 + (b) * 32768)

// stage one 128-row half-tile (16 KiB) of A or B: 2 x global_load_lds per
// thread; LDS dest wave-uniform, global source per-lane pre-swizzled.
#define STAGE_A(bufb, h, kt)                                                   \
  do {                                                                         \
    const int ko_ = ((kt) & 7) * 64;                                           \
    const uint32_t o0_ = (((kt) < 8) ? offd[h][0] : offa[h][0]) + ko_;         \
    const uint32_t o1_ = (((kt) < 8) ? offd[h][1] : offa[h][1]) + ko_;         \
    gload_lds16(Asrc + o0_, (bf16*)(A_BUF(bufb) + (h)*16384 + wave * 1024));   \
    gload_lds16(Asrc + o1_,                                                    \
                (bf16*)(A_BUF(bufb) + (h)*16384 + 8192 + wave * 1024));        \
  } while (0)

#define STAGE_B(bufb, h, kt)                                                   \
  do {                                                                         \
    const int ko_ = (kt)*64;                                                   \
    gload_lds16(Bt + offB[h][0] + ko_,                                         \
                (bf16*)(B_BUF(bufb) + (h)*16384 + wave * 1024));               \
    gload_lds16(Bt + offB[h][1] + ko_,                                         \
                (bf16*)(B_BUF(bufb) + (h)*16384 + 8192 + wave * 1024));        \
  } while (0)

// register-subtile loads (compiler inserts the lgkmcnt before MFMA use)
#define LDA(bufb, mh)                                                          \
  do {                                                                         \
    _Pragma("unroll") for (int mt = 0; mt < 4; ++mt) {                         \
      const int r_ = wm * 128 + (mh)*64 + mt * 16 + rr;                        \
      _Pragma("unroll") for (int kk = 0; kk < 2; ++kk) {                       \
        const int sl_ = (kk * 4 + q) ^ (r_ & 7);                               \
        afr[mt * 2 + kk] =                                                     \
            *(const bf16x8*)(A_BUF(bufb) + r_ * 128 + sl_ * 16);               \
      }                                                                        \
    }                                                                          \
  } while (0)

#define LDB(bufb, nh, BFR)                                                     \
  do {                                                                         \
    _Pragma("unroll") for (int nt = 0; nt < 2; ++nt) {                         \
      const int r_ = wn * 64 + (nh)*32 + nt * 16 + rr;                         \
      _Pragma("unroll") for (int kk = 0; kk < 2; ++kk) {                       \
        const int sl_ = (kk * 4 + q) ^ (r_ & 7);                               \
        BFR[nt * 2 + kk] =                                                     \
            *(const bf16x8*)(B_BUF(bufb) + r_ * 128 + sl_ * 16);               \
      }                                                                        \
    }                                                                          \
  } while (0)

#define MFMAQ(mh, nh, BFR)                                                     \
  do {                                                                         \
    _Pragma("unroll") for (int mt = 0; mt < 4; ++mt)                           \
        _Pragma("unroll") for (int nt = 0; nt < 2; ++nt)                       \
            _Pragma("unroll") for (int kk = 0; kk < 2; ++kk)                   \
                acc4[(mh)*4 + mt][(nh)*2 + nt] =                               \
        __builtin_amdgcn_mfma_f32_16x16x32_bf16(                               \
            afr[mt * 2 + kk], BFR[nt * 2 + kk],                                \
            acc4[(mh)*4 + mt][(nh)*2 + nt], 0, 0, 0);                          \
  } while (0)

#define BARRIER __builtin_amdgcn_s_barrier()
#define PRIO1 __builtin_amdgcn_s_setprio(1)
#define PRIO0 __builtin_amdgcn_s_setprio(0)
#define VMCNT4 asm volatile("s_waitcnt vmcnt(4)" ::: "memory")
#define VMCNT0 asm volatile("s_waitcnt vmcnt(0)" ::: "memory")

// MODE 0: A = gathered concat(aug[don], aug[acc]); C = relu(A@Bt^T+b) -> bf16
// MODE 1: A = H1 linear;  pot[row] += relu(A@Bt^T+b) @ w3 (atomic)
template <int MODE>
__global__ __launch_bounds__(512, 2) void gemm8_kernel(
    const bf16* __restrict__ Asrc, const int* __restrict__ don,
    const int* __restrict__ acc, const bf16* __restrict__ Bt,
    const float* __restrict__ bias, const float* __restrict__ w3,
    bf16* __restrict__ Cout, float* __restrict__ pot) {
  extern __shared__ __align__(16) char smem[];
  const int tid = threadIdx.x;
  const int wave = tid >> 6;
  const int lane = tid & 63;
  const int q = lane >> 4;
  const int rr = lane & 15;
  const int wm = wave >> 2;  // 0..1
  const int wn = wave & 3;   // 0..3

  // XCD-grouped tile map: xcd = bid&7 gets 128 consecutive linear tiles ->
  // 32 consecutive row-tiles x 4 col-tiles share A-panels in one XCD's L2.
  const int orig = blockIdx.x;
  const int L = ((orig & 7) << 7) | (orig >> 3);  // bijective, 0..1023
  const int row0 = (L >> 2) << 8;                 // 256 row tiles
  const int col0 = (L & 3) << 8;                  // 4 col tiles

  // per-thread staging source offsets (elements), 32-bit
  uint32_t offd[2][2], offa[2][2], offB[2][2];
#pragma unroll
  for (int h = 0; h < 2; ++h)
#pragma unroll
    for (int j = 0; j < 2; ++j) {
      const int rloc = (j * 512 + tid) >> 3;      // row within 128-row half
      const int g = (tid & 7) ^ (rloc & 7);       // pre-swizzled granule
      const int rA = row0 + h * 128 + rloc;
      if constexpr (MODE == 0) {
        const int b = rA >> 12;
        offd[h][j] = (uint32_t)(((uint32_t)b * NSA + don[rA]) * NC + g * 8);
        offa[h][j] = (uint32_t)(((uint32_t)b * NSA + acc[rA]) * NC + g * 8);
      } else {
        offd[h][j] = (uint32_t)((uint32_t)rA * KD + g * 8);
        offa[h][j] = offd[h][j] + 512;  // makes (kt<8?d:a)+(kt&7)*64 == kt*64
      }
      const int rB = col0 + h * 128 + rloc;
      offB[h][j] = (uint32_t)((uint32_t)rB * KD + g * 8);
    }

  bf16x8 afr[8], bfr0[4], bfr1[4];
  f32x4 acc4[8][4] = {};

  // Prologue: tile0 fully into buf0; tile1's B halves into buf1.
  // (tile1's A halves are staged in P1/P2 of iteration 0.)
  STAGE_A(0, 0, 0);
  STAGE_A(0, 1, 0);
  STAGE_B(0, 0, 0);
  STAGE_B(0, 1, 0);
  STAGE_B(1, 0, 1);
  STAGE_B(1, 1, 1);
  VMCNT4;  // first 8 loads (all of tile0) landed; tile1 B may be in flight
  BARRIER;

#pragma unroll 1
  for (int it = 0; it < 8; ++it) {
    const int t0 = 2 * it;
    const bool more = (it < 7);
    // ---- P1: compute Q(0,0) of tile t0; stage buf1.A0 (tile t0+1)
    LDA(0, 0);
    LDB(0, 0, bfr0);
    STAGE_A(1, 0, t0 + 1);
    BARRIER;
    PRIO1; MFMAQ(0, 0, bfr0); PRIO0;
    BARRIER;
    // ---- P2: Q(0,1); stage buf1.A1
    LDB(0, 1, bfr1);
    STAGE_A(1, 1, t0 + 1);
    BARRIER;
    PRIO1; MFMAQ(0, 1, bfr1); PRIO0;
    BARRIER;
    // ---- P3: Q(1,0); stage buf0.B0 (tile t0+2) [B of t0 last read in P2]
    LDA(0, 1);
    if (more) STAGE_B(0, 0, t0 + 2);
    BARRIER;
    PRIO1; MFMAQ(1, 0, bfr0); PRIO0;
    BARRIER;
    // ---- P4: Q(1,1); stage buf0.B1; counted wait for buf1 (tile t0+1)
    if (more) STAGE_B(0, 1, t0 + 2);
    BARRIER;
    PRIO1; MFMAQ(1, 1, bfr1); PRIO0;
    if (more) { VMCNT4; } else { VMCNT0; }  // allow P3/P4 stages in flight
    BARRIER;
    // ---- P5: Q(0,0) of tile t0+1 (buf1); stage buf0.A0 [A of t0 last read P3]
    LDA(1, 0);
    LDB(1, 0, bfr0);
    if (more) STAGE_A(0, 0, t0 + 2);
    BARRIER;
    PRIO1; MFMAQ(0, 0, bfr0); PRIO0;
    BARRIER;
    // ---- P6: Q(0,1); stage buf0.A1
    LDB(1, 1, bfr1);
    if (more) STAGE_A(0, 1, t0 + 2);
    BARRIER;
    PRIO1; MFMAQ(0, 1, bfr1); PRIO0;
    BARRIER;
    // ---- P7: Q(1,0); stage buf1.B0 (tile t0+3) [B of t0+1 last read P6]
    LDA(1, 1);
    if (more) STAGE_B(1, 0, t0 + 3);
    BARRIER;
    PRIO1; MFMAQ(1, 0, bfr0); PRIO0;
    BARRIER;
    // ---- P8: Q(1,1); stage buf1.B1; counted wait for buf0 (tile t0+2)
    if (more) STAGE_B(1, 1, t0 + 3);
    BARRIER;
    PRIO1; MFMAQ(1, 1, bfr1); PRIO0;
    VMCNT4;  // tile t0+2 (P3-P6 stages) landed; P7/P8 stay in flight
    BARRIER;
  }

  // Epilogue. C/D layout: col = lane&15 (=rr), row = q*4 + reg.
  // Global row = row0 + wm*128 + mt*16 + q*4 + rg; col = col0 + wn*64 + nt*16 + rr.
  if constexpr (MODE == 0) {
#pragma unroll
    for (int nt = 0; nt < 4; ++nt) {
      const int col = col0 + wn * 64 + nt * 16 + rr;
      const float bv = bias[col];
#pragma unroll
      for (int mt = 0; mt < 8; ++mt) {
        const int rbase = row0 + wm * 128 + mt * 16 + q * 4;
#pragma unroll
        for (int rg = 0; rg < 4; ++rg) {
          const float v = fmaxf(acc4[mt][nt][rg] + bv, 0.f);
          Cout[(size_t)(rbase + rg) * KD + col] = __float2bfloat16(v);
        }
      }
    }
  } else {
    float bv[4], wv[4];
#pragma unroll
    for (int nt = 0; nt < 4; ++nt) {
      const int col = col0 + wn * 64 + nt * 16 + rr;
      bv[nt] = bias[col];
      wv[nt] = w3[col];
    }
#pragma unroll
    for (int mt = 0; mt < 8; ++mt) {
#pragma unroll
      for (int rg = 0; rg < 4; ++rg) {
        float s = 0.f;
#pragma unroll
        for (int nt = 0; nt < 4; ++nt)
          s += fmaxf(acc4[mt][nt][rg] + bv[nt], 0.f) * wv[nt];
        s += __shfl_xor(s, 1);
        s += __shfl_xor(s, 2);
        s += __shfl_xor(s, 4);
        s += __shfl_xor(s, 8);
        if (rr == 0) {
          const int row = row0 + wm * 128 + mt * 16 + q * 4 + rg;
          atomicAdd(&pot[row], s);
        }
      }
    }
  }
}

// ---------------------------------------------------------------------------
// Fused prep kernel, disjoint block ranges:
//   [0, 2048)               : W1/W2 transpose+cast 32x32 tiles -> W1t/W2t
//   [2048, 2048+16392)      : augmented bf16 site table (4 rows/block)
//   [+16392, +16392+64)     : zero pot
__global__ void prep_kernel(const float* __restrict__ W1,
                            bf16* __restrict__ W1t,
                            const float* __restrict__ W2,
                            bf16* __restrict__ W2t,
                            const float* __restrict__ ssr,
                            const float* __restrict__ gstart,
                            const float* __restrict__ gend,
                            bf16* __restrict__ aug,
                            float* __restrict__ pot) {
  const int bid = blockIdx.x;
  const int tid = threadIdx.x;
  if (bid < PREP_W_BLKS) {
    // ---- weight transpose+cast ----
    __shared__ bf16 tile[32][33];
    const float* W = (bid >= 1024) ? W2 : W1;
    bf16* Wt = (bid >= 1024) ? W2t : W1t;
    const int pos = bid & 1023;
    const int n0 = (pos & 31) * 32;
    const int k0 = (pos >> 5) * 32;
    const int c = tid & 31;
    const int r0 = tid >> 5;  // 0..7
#pragma unroll
    for (int i = 0; i < 4; i++) {
      int r = r0 + i * 8;
      tile[r][c] = __float2bfloat16(W[(size_t)(k0 + r) * KD + (n0 + c)]);
    }
    __syncthreads();
#pragma unroll
    for (int i = 0; i < 4; i++) {
      int r = r0 + i * 8;  // n-row of output
      Wt[(size_t)(n0 + r) * KD + (k0 + c)] = tile[c][r];
    }
  } else if (bid < PREP_W_BLKS + PREP_AUG_BLKS) {
    // ---- aug table: 4 rows per block, one wave per row, dense 16B loads ----
    const int row = (bid - PREP_W_BLKS) * 4 + (tid >> 6);  // 0..NB*NSA-1
    const int i = tid & 63;                                 // lane
    const int b = row / NSA;
    const int s = row - b * NSA;
    const float* src;
    if (s < NS)       src = ssr + ((size_t)b * NS + s) * NC;
    else if (s == NS) src = gstart;
    else              src = gend;
    f32x4 f0 = *(const f32x4*)(src + 4 * i);        // floats [4i, 4i+4)
    f32x4 f1 = *(const f32x4*)(src + 256 + 4 * i);  // floats [256+4i, ..)
    bf16* dst = aug + (size_t)row * NC;
    union { uint64_t u; bf16 e[4]; } a, b4;
    a.e[0] = __float2bfloat16(f0.x); a.e[1] = __float2bfloat16(f0.y);
    a.e[2] = __float2bfloat16(f0.z); a.e[3] = __float2bfloat16(f0.w);
    b4.e[0] = __float2bfloat16(f1.x); b4.e[1] = __float2bfloat16(f1.y);
    b4.e[2] = __float2bfloat16(f1.z); b4.e[3] = __float2bfloat16(f1.w);
    *(uint64_t*)(dst + 4 * i) = a.u;
    *(uint64_t*)(dst + 256 + 4 * i) = b4.u;
  } else {
    // ---- zero pot: 64 blocks x 256 threads x 4 floats = 65536 ----
    const int i = (bid - (PREP_W_BLKS + PREP_AUG_BLKS)) * 1024 + tid * 4;
    *(f32x4*)(pot + i) = (f32x4){0.f, 0.f, 0.f, 0.f};
  }
}

// ---------------------------------------------------------------------------
// Per-gene transcript potential sum + softmax over T+1 entries.
__global__ void transcript_softmax_kernel(const float* __restrict__ pot,
                                          const int* __restrict__ tj,
                                          const float* __restrict__ b3,
                                          const float* __restrict__ refp,
                                          float* __restrict__ out) {
  const int b = blockIdx.x;
  const int t = threadIdx.x;  // 64 threads = 1 wave
  const int* tjb = tj + ((size_t)b * NT + t) * NKJ;
  float s = 0.f;
#pragma unroll
  for (int k = 0; k < NKJ; k++) s += pot[b * NJ + tjb[k]];
  s += (float)NKJ * b3[0];
  const float ref = refp[0];
  float m = fmaxf(s, ref);
#pragma unroll
  for (int o = 1; o < 64; o <<= 1) m = fmaxf(m, __shfl_xor(m, o));
  const float e = expf(s - m);
  float denom = e;
#pragma unroll
  for (int o = 1; o < 64; o <<= 1) denom += __shfl_xor(denom, o);
  const float eref = expf(ref - m);
  denom += eref;
  out[b * (NT + 1) + t] = e / denom;
  if (t == 0) out[b * (NT + 1) + NT] = eref / denom;
}

// ---------------------------------------------------------------------------
extern "C" void kernel_launch(void* const* d_in, const int* in_sizes, int n_in,
                              void* d_out, int out_size, void* d_ws,
                              size_t ws_size, hipStream_t stream) {
  const float* ssr    = (const float*)d_in[0];   // [16,4096,512]
  const int*   don    = (const int*)d_in[1];     // [16,4096]
  const int*   acc    = (const int*)d_in[2];     // [16,4096]
  const int*   tj     = (const int*)d_in[3];     // [16,64,32]
  const float* W1     = (const float*)d_in[4];   // [1024,1024]
  const float* b1     = (const float*)d_in[5];   // [1024]
  const float* W2     = (const float*)d_in[6];   // [1024,1024]
  const float* b2     = (const float*)d_in[7];   // [1024]
  const float* W3     = (const float*)d_in[8];   // [1024,1]
  const float* b3     = (const float*)d_in[9];   // [1]
  const float* gstart = (const float*)d_in[10];  // [512]
  const float* gend   = (const float*)d_in[11];  // [512]
  const float* refp   = (const float*)d_in[12];  // [1]
  float* out = (float*)d_out;                    // [16,65]

  // workspace layout (~210 MiB)
  char* ws = (char*)d_ws;
  bf16* W1t = (bf16*)ws;                 ws += (size_t)KD * KD * 2;
  bf16* W2t = (bf16*)ws;                 ws += (size_t)KD * KD * 2;
  bf16* aug = (bf16*)ws;                 ws += (size_t)NB * NSA * NC * 2;
  bf16* H1  = (bf16*)ws;                 ws += (size_t)NM * KD * 2;
  float* pot = (float*)ws;               ws += (size_t)NM * 4;

  prep_kernel<<<PREP_W_BLKS + PREP_AUG_BLKS + PREP_POT_BLKS, 256, 0, stream>>>(
      W1, W1t, W2, W2t, ssr, gstart, gend, aug, pot);

  gemm8_kernel<0><<<1024, 512, 131072, stream>>>(
      aug, don, acc, W1t, b1, nullptr, H1, nullptr);

  gemm8_kernel<1><<<1024, 512, 131072, stream>>>(
      H1, nullptr, nullptr, W2t, b2, W3, nullptr, pot);

  transcript_softmax_kernel<<<NB, 64, 0, stream>>>(pot, tj, b3, refp, out);
}

// Round 2
// 367.233 us; speedup vs baseline: 1.4111x; 1.4111x over previous
//
#include <hip/hip_runtime.h>
#include <hip/hip_bf16.h>
#include <stdint.h>
#include <stddef.h>

// Problem constants (match reference)
#define NB 16       // genes
#define NS 4096     // splice sites per gene
#define NSA 4098    // augmented sites (incl. gene_start, gene_end)
#define NC 512      // channels per site rep
#define NJ 4096     // junctions per gene
#define NT 64       // transcripts per gene
#define NKJ 32      // junctions per transcript
#define KD 1024     // 2*NC = MLP in/hidden dim

// Compaction: only junctions referenced by transcript_junctions need pot.
// T*K = 2048 slots/gene -> distinct used junctions <= 2048. Pad each gene's
// compact list to exactly NJC rows (fixed grid), compute MLP only on those.
#define NJC 2048                 // compact rows per gene (padded)
#define NMC (NB * NJC)           // 32768 GEMM rows (half of naive 65536)

// prep kernel block ranges
#define PREP_W_BLKS 2048                    // weight transpose tiles
#define PREP_AUG_BLKS ((NB * NSA) / 4)      // 16392: aug rows / 4
#define PREP_POT_BLKS 32                    // pot zeroing (32768 floats)

typedef __hip_bfloat16 bf16;
typedef __attribute__((ext_vector_type(8))) short bf16x8;  // 8 bf16 = 4 VGPRs
typedef __attribute__((ext_vector_type(4))) float f32x4;

// GEMM tile geometry: BM=128 x BN=128 x BK=64, 4 waves (2x2),
// 4x4 16x16x32 MFMA per wave. LDS 16B-granule XOR swizzle: logical
// (row m, granule g) stored at slot m*8 + (g ^ (m&7)).
#define BM 128
#define BN 128
#define BK 64

// async global->LDS, 16B per lane. Global address is PER-LANE (gather ok);
// LDS dest = wave-uniform base + lane*16.
__device__ __forceinline__ void gload_lds16(const bf16* g, bf16* l) {
  __builtin_amdgcn_global_load_lds(
      (const __attribute__((address_space(1))) void*)g,
      (__attribute__((address_space(3))) void*)l, 16, 0, 0);
}

// XCD-aware tile swizzle: HW round-robins blockIdx%8 across the 8 XCDs.
// Make the 8 col-blocks that share one 128-row A-stripe land on ONE XCD:
// bid = hi*64 + c*8 + lo  ->  row_idx = hi*8+lo, col_idx = c (0..7).
// Bijective for any grid that is a multiple of 64 blocks.
__device__ __forceinline__ void tile_from_bid(int bid, int& row0, int& col0) {
  const int row_idx = ((bid >> 6) << 3) | (bid & 7);
  const int col_idx = (bid >> 3) & 7;  // 0..7
  row0 = row_idx * BM;
  col0 = col_idx * BN;
}

// ---------------------------------------------------------------------------
// Compaction: per gene, mark used junctions (LDS flags), exclusive-scan,
// emit compact row list + inverse position map. One block per gene.
__global__ __launch_bounds__(1024) void compact_kernel(
    const int* __restrict__ tj,     // [16,64,32] flat
    int* __restrict__ rows_list,    // [NB*NJC] junction id per compact row
    int* __restrict__ pmap) {       // [NB*NJ]  junction -> compact position
  const int b = blockIdx.x;
  const int tid = threadIdx.x;  // 0..1023
  __shared__ unsigned char flg[NJ];
  __shared__ int psum[1024];
  *(uint32_t*)&flg[tid * 4] = 0u;
  __syncthreads();
#pragma unroll
  for (int k = 0; k < 2; k++) {
    const int j = tj[b * (NT * NKJ) + tid * 2 + k];
    flg[j] = 1;  // benign races: same value
  }
  __syncthreads();
  const int j0 = tid * 4;
  const int f0 = flg[j0], f1 = flg[j0 + 1], f2 = flg[j0 + 2], f3 = flg[j0 + 3];
  const int ls = f0 + f1 + f2 + f3;
  psum[tid] = ls;
  __syncthreads();
  // Hillis-Steele inclusive scan over 1024 entries
  for (int o = 1; o < 1024; o <<= 1) {
    const int v = (tid >= o) ? psum[tid - o] : 0;
    __syncthreads();
    psum[tid] += v;
    __syncthreads();
  }
  const int total = psum[1023];
  int p = psum[tid] - ls;  // exclusive prefix
  if (f0) { rows_list[b * NJC + p] = j0;     pmap[b * NJ + j0]     = p; p++; }
  if (f1) { rows_list[b * NJC + p] = j0 + 1; pmap[b * NJ + j0 + 1] = p; p++; }
  if (f2) { rows_list[b * NJC + p] = j0 + 2; pmap[b * NJ + j0 + 2] = p; p++; }
  if (f3) { rows_list[b * NJC + p] = j0 + 3; pmap[b * NJ + j0 + 3] = p; p++; }
  // pad tail with junction 0 (computed but never read)
  for (int i = total + tid; i < NJC; i += 1024) rows_list[b * NJC + i] = 0;
}

// ---------------------------------------------------------------------------
// Fused prep kernel, disjoint block ranges:
//   [0, 2048)               : W1/W2 transpose+cast 32x32 tiles -> W1t/W2t
//   [2048, 2048+16392)      : augmented bf16 site table (4 rows/block)
//   [+16392, +16392+32)     : zero pot (32768 floats)
__global__ void prep_kernel(const float* __restrict__ W1,
                            bf16* __restrict__ W1t,
                            const float* __restrict__ W2,
                            bf16* __restrict__ W2t,
                            const float* __restrict__ ssr,
                            const float* __restrict__ gstart,
                            const float* __restrict__ gend,
                            bf16* __restrict__ aug,
                            float* __restrict__ pot) {
  const int bid = blockIdx.x;
  const int tid = threadIdx.x;
  if (bid < PREP_W_BLKS) {
    // ---- weight transpose+cast ----
    __shared__ bf16 tile[32][33];
    const float* W = (bid >= 1024) ? W2 : W1;
    bf16* Wt = (bid >= 1024) ? W2t : W1t;
    const int pos = bid & 1023;
    const int n0 = (pos & 31) * 32;
    const int k0 = (pos >> 5) * 32;
    const int c = tid & 31;
    const int r0 = tid >> 5;  // 0..7
#pragma unroll
    for (int i = 0; i < 4; i++) {
      int r = r0 + i * 8;
      tile[r][c] = __float2bfloat16(W[(size_t)(k0 + r) * KD + (n0 + c)]);
    }
    __syncthreads();
#pragma unroll
    for (int i = 0; i < 4; i++) {
      int r = r0 + i * 8;  // n-row of output
      Wt[(size_t)(n0 + r) * KD + (k0 + c)] = tile[c][r];
    }
  } else if (bid < PREP_W_BLKS + PREP_AUG_BLKS) {
    // ---- aug table: 4 rows per block, one wave per row, dense 16B loads ----
    const int row = (bid - PREP_W_BLKS) * 4 + (tid >> 6);  // 0..NB*NSA-1
    const int i = tid & 63;                                 // lane
    const int b = row / NSA;
    const int s = row - b * NSA;
    const float* src;
    if (s < NS)       src = ssr + ((size_t)b * NS + s) * NC;
    else if (s == NS) src = gstart;
    else              src = gend;
    f32x4 f0 = *(const f32x4*)(src + 4 * i);        // floats [4i, 4i+4)
    f32x4 f1 = *(const f32x4*)(src + 256 + 4 * i);  // floats [256+4i, ..)
    bf16* dst = aug + (size_t)row * NC;
    union { uint64_t u; bf16 e[4]; } a, b4;
    a.e[0] = __float2bfloat16(f0.x); a.e[1] = __float2bfloat16(f0.y);
    a.e[2] = __float2bfloat16(f0.z); a.e[3] = __float2bfloat16(f0.w);
    b4.e[0] = __float2bfloat16(f1.x); b4.e[1] = __float2bfloat16(f1.y);
    b4.e[2] = __float2bfloat16(f1.z); b4.e[3] = __float2bfloat16(f1.w);
    *(uint64_t*)(dst + 4 * i) = a.u;
    *(uint64_t*)(dst + 256 + 4 * i) = b4.u;
  } else {
    // ---- zero pot: 32 blocks x 256 threads x 4 floats = 32768 ----
    const int i = (bid - (PREP_W_BLKS + PREP_AUG_BLKS)) * 1024 + tid * 4;
    *(f32x4*)(pot + i) = (f32x4){0.f, 0.f, 0.f, 0.f};
  }
}

// ---------------------------------------------------------------------------
// GEMM1 with fused gather via async DMA: compact row r -> junction
// jid = rows_list[r]; A row = concat(aug[don[jid]], aug[acc[jid]]) in bf16.
// C = relu(A @ W1t^T + b1) stored bf16.
__global__ __launch_bounds__(256, 2) void gemm1_gather_kernel(
    const bf16* __restrict__ aug, const int* __restrict__ don,
    const int* __restrict__ acc, const int* __restrict__ rows_list,
    const bf16* __restrict__ Bt, const float* __restrict__ bias,
    bf16* __restrict__ Cout) {
  __shared__ __align__(16) bf16 As[BM * BK];
  __shared__ __align__(16) bf16 Bs[BN * BK];
  const int tid = threadIdx.x;
  const int wave = tid >> 6;
  const int lane = tid & 63;
  int row0, col0;
  tile_from_bid(blockIdx.x, row0, col0);
  const int wm = wave & 1;
  const int wn = wave >> 1;
  const int q = lane >> 4;
  const int rr = lane & 15;

  // staging descriptors: LDS slot L covers logical (row m, granule g)
  int mm[4], gg[4];
#pragma unroll
  for (int i = 0; i < 4; i++) {
    int L = wave * 256 + i * 64 + lane;
    int m = L >> 3;
    int g = (L & 7) ^ (m & 7);
    mm[i] = m; gg[i] = g;
  }

  // per-lane gathered A row base pointers (don half / acc half of K)
  const bf16* dp[4];
  const bf16* ap[4];
#pragma unroll
  for (int i = 0; i < 4; i++) {
    const int r = row0 + mm[i];
    const int b = r >> 11;              // NJC = 2048 rows per gene
    const int jid = rows_list[r];
    dp[i] = aug + ((size_t)b * NSA + don[b * NJ + jid]) * NC;
    ap[i] = aug + ((size_t)b * NSA + acc[b * NJ + jid]) * NC;
  }

  f32x4 acc4[4][4] = {};

  for (int kt = 0; kt < KD / BK; ++kt) {
    const int ko = (kt & 7) * BK;  // offset within the 512-wide half
#pragma unroll
    for (int i = 0; i < 4; i++) {
      const bf16* abase = (kt < 8) ? dp[i] : ap[i];
      gload_lds16(abase + ko + gg[i] * 8,
                  As + (size_t)(wave * 256 + i * 64) * 8);
      gload_lds16(Bt + ((size_t)(col0 + mm[i]) * KD + kt * BK + gg[i] * 8),
                  Bs + (size_t)(wave * 256 + i * 64) * 8);
    }
    __syncthreads();
#pragma unroll
    for (int kk = 0; kk < 2; ++kk) {
      bf16x8 afr[4], bfr[4];
      const int g = kk * 4 + q;
#pragma unroll
      for (int mt = 0; mt < 4; mt++) {
        int m = wm * 64 + mt * 16 + rr;
        afr[mt] = *(const bf16x8*)(As + (m * 8 + (g ^ (m & 7))) * 8);
      }
#pragma unroll
      for (int nt = 0; nt < 4; nt++) {
        int n = wn * 64 + nt * 16 + rr;
        bfr[nt] = *(const bf16x8*)(Bs + (n * 8 + (g ^ (n & 7))) * 8);
      }
#pragma unroll
      for (int mt = 0; mt < 4; mt++)
#pragma unroll
        for (int nt = 0; nt < 4; nt++)
          acc4[mt][nt] = __builtin_amdgcn_mfma_f32_16x16x32_bf16(
              afr[mt], bfr[nt], acc4[mt][nt], 0, 0, 0);
    }
    __syncthreads();
  }

  // Epilogue. C/D layout: col = lane&15, row = quad*4 + reg
#pragma unroll
  for (int nt = 0; nt < 4; nt++) {
    const int col = col0 + wn * 64 + nt * 16 + rr;
    const float bv = bias[col];
#pragma unroll
    for (int mt = 0; mt < 4; mt++) {
      const int rbase = row0 + wm * 64 + mt * 16 + q * 4;
#pragma unroll
      for (int rg = 0; rg < 4; rg++) {
        float v = fmaxf(acc4[mt][nt][rg] + bv, 0.f);
        Cout[(size_t)(rbase + rg) * KD + col] = __float2bfloat16(v);
      }
    }
  }
}

// ---------------------------------------------------------------------------
// GEMM2: pot contribution = relu(H1 @ W2t^T + b2) @ w3, atomicAdd per row.
__global__ __launch_bounds__(256, 2) void gemm2_kernel(
    const bf16* __restrict__ A, const bf16* __restrict__ Bt,
    const float* __restrict__ bias, const float* __restrict__ w3,
    float* __restrict__ pot) {
  __shared__ __align__(16) bf16 As[BM * BK];
  __shared__ __align__(16) bf16 Bs[BN * BK];
  const int tid = threadIdx.x;
  const int wave = tid >> 6;
  const int lane = tid & 63;
  int row0, col0;
  tile_from_bid(blockIdx.x, row0, col0);
  const int wm = wave & 1;
  const int wn = wave >> 1;
  const int q = lane >> 4;
  const int rr = lane & 15;

  int mm[4], gg[4];
#pragma unroll
  for (int i = 0; i < 4; i++) {
    int L = wave * 256 + i * 64 + lane;
    int m = L >> 3;
    int g = (L & 7) ^ (m & 7);
    mm[i] = m; gg[i] = g;
  }

  f32x4 acc4[4][4] = {};

  for (int kt = 0; kt < KD / BK; ++kt) {
#pragma unroll
    for (int i = 0; i < 4; i++) {
      gload_lds16(A + ((size_t)(row0 + mm[i]) * KD + kt * BK + gg[i] * 8),
                  As + (size_t)(wave * 256 + i * 64) * 8);
      gload_lds16(Bt + ((size_t)(col0 + mm[i]) * KD + kt * BK + gg[i] * 8),
                  Bs + (size_t)(wave * 256 + i * 64) * 8);
    }
    __syncthreads();
#pragma unroll
    for (int kk = 0; kk < 2; ++kk) {
      bf16x8 afr[4], bfr[4];
      const int g = kk * 4 + q;
#pragma unroll
      for (int mt = 0; mt < 4; mt++) {
        int m = wm * 64 + mt * 16 + rr;
        afr[mt] = *(const bf16x8*)(As + (m * 8 + (g ^ (m & 7))) * 8);
      }
#pragma unroll
      for (int nt = 0; nt < 4; nt++) {
        int n = wn * 64 + nt * 16 + rr;
        bfr[nt] = *(const bf16x8*)(Bs + (n * 8 + (g ^ (n & 7))) * 8);
      }
#pragma unroll
      for (int mt = 0; mt < 4; mt++)
#pragma unroll
        for (int nt = 0; nt < 4; nt++)
          acc4[mt][nt] = __builtin_amdgcn_mfma_f32_16x16x32_bf16(
              afr[mt], bfr[nt], acc4[mt][nt], 0, 0, 0);
    }
    __syncthreads();
  }

  float bv[4], wv[4];
#pragma unroll
  for (int nt = 0; nt < 4; nt++) {
    const int col = col0 + wn * 64 + nt * 16 + rr;
    bv[nt] = bias[col];
    wv[nt] = w3[col];
  }
#pragma unroll
  for (int mt = 0; mt < 4; mt++) {
#pragma unroll
    for (int rg = 0; rg < 4; rg++) {
      float s = 0.f;
#pragma unroll
      for (int nt = 0; nt < 4; nt++)
        s += fmaxf(acc4[mt][nt][rg] + bv[nt], 0.f) * wv[nt];
      s += __shfl_xor(s, 1);
      s += __shfl_xor(s, 2);
      s += __shfl_xor(s, 4);
      s += __shfl_xor(s, 8);
      if (rr == 0) {
        int row = row0 + wm * 64 + mt * 16 + q * 4 + rg;
        atomicAdd(&pot[row], s);
      }
    }
  }
}

// ---------------------------------------------------------------------------
// Per-gene transcript potential sum + softmax over T+1 entries.
// pot is compact: junction j of gene b lives at pot[b*NJC + pmap[b*NJ + j]].
__global__ void transcript_softmax_kernel(const float* __restrict__ pot,
                                          const int* __restrict__ tj,
                                          const int* __restrict__ pmap,
                                          const float* __restrict__ b3,
                                          const float* __restrict__ refp,
                                          float* __restrict__ out) {
  const int b = blockIdx.x;
  const int t = threadIdx.x;  // 64 threads = 1 wave
  const int* tjb = tj + ((size_t)b * NT + t) * NKJ;
  const int* pm = pmap + (size_t)b * NJ;
  const float* pb = pot + (size_t)b * NJC;
  float s = 0.f;
#pragma unroll
  for (int k = 0; k < NKJ; k++) s += pb[pm[tjb[k]]];
  s += (float)NKJ * b3[0];
  const float ref = refp[0];
  float m = fmaxf(s, ref);
#pragma unroll
  for (int o = 1; o < 64; o <<= 1) m = fmaxf(m, __shfl_xor(m, o));
  const float e = expf(s - m);
  float denom = e;
#pragma unroll
  for (int o = 1; o < 64; o <<= 1) denom += __shfl_xor(denom, o);
  const float eref = expf(ref - m);
  denom += eref;
  out[b * (NT + 1) + t] = e / denom;
  if (t == 0) out[b * (NT + 1) + NT] = eref / denom;
}

// ---------------------------------------------------------------------------
extern "C" void kernel_launch(void* const* d_in, const int* in_sizes, int n_in,
                              void* d_out, int out_size, void* d_ws,
                              size_t ws_size, hipStream_t stream) {
  const float* ssr    = (const float*)d_in[0];   // [16,4096,512]
  const int*   don    = (const int*)d_in[1];     // [16,4096]
  const int*   acc    = (const int*)d_in[2];     // [16,4096]
  const int*   tj     = (const int*)d_in[3];     // [16,64,32]
  const float* W1     = (const float*)d_in[4];   // [1024,1024]
  const float* b1     = (const float*)d_in[5];   // [1024]
  const float* W2     = (const float*)d_in[6];   // [1024,1024]
  const float* b2     = (const float*)d_in[7];   // [1024]
  const float* W3     = (const float*)d_in[8];   // [1024,1]
  const float* b3     = (const float*)d_in[9];   // [1]
  const float* gstart = (const float*)d_in[10];  // [512]
  const float* gend   = (const float*)d_in[11];  // [512]
  const float* refp   = (const float*)d_in[12];  // [1]
  float* out = (float*)d_out;                    // [16,65]

  // workspace layout (~140 MiB)
  char* ws = (char*)d_ws;
  bf16* W1t = (bf16*)ws;                 ws += (size_t)KD * KD * 2;
  bf16* W2t = (bf16*)ws;                 ws += (size_t)KD * KD * 2;
  bf16* aug = (bf16*)ws;                 ws += (size_t)NB * NSA * NC * 2;
  bf16* H1  = (bf16*)ws;                 ws += (size_t)NMC * KD * 2;
  float* pot = (float*)ws;               ws += (size_t)NMC * 4;
  int* rows_list = (int*)ws;             ws += (size_t)NB * NJC * 4;
  int* pmap = (int*)ws;                  ws += (size_t)NB * NJ * 4;

  compact_kernel<<<NB, 1024, 0, stream>>>(tj, rows_list, pmap);

  prep_kernel<<<PREP_W_BLKS + PREP_AUG_BLKS + PREP_POT_BLKS, 256, 0, stream>>>(
      W1, W1t, W2, W2t, ssr, gstart, gend, aug, pot);

  gemm1_gather_kernel<<<NMC / BM * (KD / BN), 256, 0, stream>>>(
      aug, don, acc, rows_list, W1t, b1, H1);

  gemm2_kernel<<<NMC / BM * (KD / BN), 256, 0, stream>>>(H1, W2t, b2, W3, pot);

  transcript_softmax_kernel<<<NB, 64, 0, stream>>>(pot, tj, pmap, b3, refp, out);
}

// Round 3
// 326.039 us; speedup vs baseline: 1.5894x; 1.1263x over previous
//
#include <hip/hip_runtime.h>
#include <hip/hip_bf16.h>
#include <stdint.h>
#include <stddef.h>

// Problem constants (match reference)
#define NB 16       // genes
#define NS 4096     // splice sites per gene
#define NSA 4098    // augmented sites (incl. gene_start, gene_end)
#define SFS 4104    // sflag per-gene stride (NSA padded to multiple of 8)
#define NC 512      // channels per site rep
#define NJ 4096     // junctions per gene
#define NT 64       // transcripts per gene
#define NKJ 32      // junctions per transcript
#define KD 1024     // 2*NC = MLP in/hidden dim

// Compaction: only junctions referenced by transcript_junctions need pot.
// Per gene: distinct used junctions cnt[b] <= 2048 (avg ~1612). Compact rows
// live at [b*NJC, b*NJC+cnt[b]); GEMMs process ceil(cnt[b]/128) tiles per
// gene via a dynamic tile map (grid = worst case, extra blocks exit early).
#define NJC 2048                 // compact region stride per gene
#define NMC (NB * NJC)           // 32768 compact rows (worst case)

// prep kernel block ranges
#define PREP_W_BLKS 2048                    // weight transpose tiles
#define PREP_AUG_BLKS ((NB * NSA) / 4)      // 16392: aug rows / 4
#define PREP_POT_BLKS 32                    // pot zeroing (32768 floats)

typedef __hip_bfloat16 bf16;
typedef __attribute__((ext_vector_type(8))) short bf16x8;  // 8 bf16 = 4 VGPRs
typedef __attribute__((ext_vector_type(4))) float f32x4;

// GEMM tile geometry: BM=128 x BN=128 x BK=64, 4 waves (2x2),
// 4x4 16x16x32 MFMA per wave. LDS 16B-granule XOR swizzle: logical
// (row m, granule g) stored at slot m*8 + (g ^ (m&7)).
#define BM 128
#define BN 128
#define BK 64

// async global->LDS, 16B per lane. Global address is PER-LANE (gather ok);
// LDS dest = wave-uniform base + lane*16.
__device__ __forceinline__ void gload_lds16(const bf16* g, bf16* l) {
  __builtin_amdgcn_global_load_lds(
      (const __attribute__((address_space(1))) void*)g,
      (__attribute__((address_space(3))) void*)l, 16, 0, 0);
}

// XCD-aware tile swizzle: HW round-robins blockIdx%8 across the 8 XCDs.
// bid = hi*64 + c*8 + lo -> row_idx = hi*8+lo, col_idx = c (0..7).
// Bijective for grids that are a multiple of 64 blocks.
__device__ __forceinline__ void tile_from_bid(int bid, int& row_idx,
                                              int& col_idx) {
  row_idx = ((bid >> 6) << 3) | (bid & 7);
  col_idx = (bid >> 3) & 7;
}

// Dynamic row-tile -> (gene, local tile) map through per-gene counts.
// Returns local tile index; gene in b_out, or b_out = -1 if past the end.
__device__ __forceinline__ int map_tile(const int* __restrict__ cnt,
                                        int row_tile, int& b_out) {
  int at = 0;
#pragma unroll
  for (int b = 0; b < NB; b++) {
    const int g = (cnt[b] + (BM - 1)) >> 7;  // tiles for gene b
    if (row_tile < at + g) { b_out = b; return row_tile - at; }
    at += g;
  }
  b_out = -1;
  return 0;
}

// ---------------------------------------------------------------------------
// Compaction: per gene, mark used junctions (LDS flags), wave-shuffle scan,
// emit compact row list + inverse position map + per-gene count + used-site
// flags (so aug prep can skip never-gathered site rows). One block per gene.
__global__ __launch_bounds__(1024) void compact_kernel(
    const int* __restrict__ tj,       // [16,64,32] flat
    const int* __restrict__ don,      // [16,4096]
    const int* __restrict__ acc,      // [16,4096]
    int* __restrict__ rows_list,      // [NB*NJC] junction id per compact row
    int* __restrict__ pmap,           // [NB*NJ]  junction -> compact position
    int* __restrict__ cnt,            // [NB] distinct used junctions
    unsigned char* __restrict__ sflag) {  // [NB*SFS] site used flags
  const int b = blockIdx.x;
  const int tid = threadIdx.x;  // 0..1023
  const int lane = tid & 63;
  const int wv = tid >> 6;  // 0..15
  __shared__ unsigned char flg[NJ];
  __shared__ int wtot[16];

  // zero junction flags (LDS) + this gene's sflag region (global)
  *(uint32_t*)&flg[tid * 4] = 0u;
  unsigned char* sf = sflag + (size_t)b * SFS;
  ((uint32_t*)sf)[tid] = 0u;
  if (tid < SFS / 4 - 1024) ((uint32_t*)sf)[1024 + tid] = 0u;
  __syncthreads();

  // mark used junctions; force junction 0 used (pad rows gather its sites)
#pragma unroll
  for (int k = 0; k < 2; k++) {
    const int j = tj[b * (NT * NKJ) + tid * 2 + k];
    flg[j] = 1;  // benign races: same value
  }
  if (tid == 0) flg[0] = 1;
  __syncthreads();

  const int j0 = tid * 4;
  const int f0 = flg[j0], f1 = flg[j0 + 1], f2 = flg[j0 + 2], f3 = flg[j0 + 3];
  const int ls = f0 + f1 + f2 + f3;

  // wave-level inclusive scan (no barriers)
  int x = ls;
#pragma unroll
  for (int o = 1; o < 64; o <<= 1) {
    const int y = __shfl_up(x, o);
    if (lane >= o) x += y;
  }
  if (lane == 63) wtot[wv] = x;
  __syncthreads();

  int woff = 0, total = 0;
#pragma unroll
  for (int w = 0; w < 16; w++) {
    const int t = wtot[w];
    if (w < wv) woff += t;
    total += t;
  }
  int p = woff + x - ls;  // exclusive prefix over the gene

  const int* donb = don + (size_t)b * NJ;
  const int* accb = acc + (size_t)b * NJ;
  int* rl = rows_list + (size_t)b * NJC;
  int* pm = pmap + (size_t)b * NJ;
  if (f0) { rl[p] = j0;     pm[j0]     = p; sf[donb[j0]]     = 1; sf[accb[j0]]     = 1; p++; }
  if (f1) { rl[p] = j0 + 1; pm[j0 + 1] = p; sf[donb[j0 + 1]] = 1; sf[accb[j0 + 1]] = 1; p++; }
  if (f2) { rl[p] = j0 + 2; pm[j0 + 2] = p; sf[donb[j0 + 2]] = 1; sf[accb[j0 + 2]] = 1; p++; }
  if (f3) { rl[p] = j0 + 3; pm[j0 + 3] = p; sf[donb[j0 + 3]] = 1; sf[accb[j0 + 3]] = 1; p++; }

  // pad tail with junction 0 (computed but never read)
  for (int i = total + tid; i < NJC; i += 1024) rl[i] = 0;
  if (tid == 0) cnt[b] = total;
}

// ---------------------------------------------------------------------------
// Fused prep kernel, disjoint block ranges:
//   [0, 2048)               : W1/W2 transpose+cast 32x32 tiles -> W1t/W2t
//   [2048, 2048+16392)      : augmented bf16 site table (4 rows/block),
//                             skipping rows whose site is never gathered
//   [+16392, +16392+32)     : zero pot (32768 floats)
__global__ void prep_kernel(const float* __restrict__ W1,
                            bf16* __restrict__ W1t,
                            const float* __restrict__ W2,
                            bf16* __restrict__ W2t,
                            const float* __restrict__ ssr,
                            const float* __restrict__ gstart,
                            const float* __restrict__ gend,
                            const unsigned char* __restrict__ sflag,
                            bf16* __restrict__ aug,
                            float* __restrict__ pot) {
  const int bid = blockIdx.x;
  const int tid = threadIdx.x;
  if (bid < PREP_W_BLKS) {
    // ---- weight transpose+cast ----
    __shared__ bf16 tile[32][33];
    const float* W = (bid >= 1024) ? W2 : W1;
    bf16* Wt = (bid >= 1024) ? W2t : W1t;
    const int pos = bid & 1023;
    const int n0 = (pos & 31) * 32;
    const int k0 = (pos >> 5) * 32;
    const int c = tid & 31;
    const int r0 = tid >> 5;  // 0..7
#pragma unroll
    for (int i = 0; i < 4; i++) {
      int r = r0 + i * 8;
      tile[r][c] = __float2bfloat16(W[(size_t)(k0 + r) * KD + (n0 + c)]);
    }
    __syncthreads();
#pragma unroll
    for (int i = 0; i < 4; i++) {
      int r = r0 + i * 8;  // n-row of output
      Wt[(size_t)(n0 + r) * KD + (k0 + c)] = tile[c][r];
    }
  } else if (bid < PREP_W_BLKS + PREP_AUG_BLKS) {
    // ---- aug table: 4 rows per block, one wave per row, dense 16B loads ----
    const int row = (bid - PREP_W_BLKS) * 4 + (tid >> 6);  // 0..NB*NSA-1
    const int i = tid & 63;                                 // lane
    const int b = row / NSA;
    const int s = row - b * NSA;
    if (!sflag[(size_t)b * SFS + s]) return;  // wave-uniform skip
    const float* src;
    if (s < NS)       src = ssr + ((size_t)b * NS + s) * NC;
    else if (s == NS) src = gstart;
    else              src = gend;
    f32x4 f0 = *(const f32x4*)(src + 4 * i);        // floats [4i, 4i+4)
    f32x4 f1 = *(const f32x4*)(src + 256 + 4 * i);  // floats [256+4i, ..)
    bf16* dst = aug + (size_t)row * NC;
    union { uint64_t u; bf16 e[4]; } a, b4;
    a.e[0] = __float2bfloat16(f0.x); a.e[1] = __float2bfloat16(f0.y);
    a.e[2] = __float2bfloat16(f0.z); a.e[3] = __float2bfloat16(f0.w);
    b4.e[0] = __float2bfloat16(f1.x); b4.e[1] = __float2bfloat16(f1.y);
    b4.e[2] = __float2bfloat16(f1.z); b4.e[3] = __float2bfloat16(f1.w);
    *(uint64_t*)(dst + 4 * i) = a.u;
    *(uint64_t*)(dst + 256 + 4 * i) = b4.u;
  } else {
    // ---- zero pot: 32 blocks x 256 threads x 4 floats = 32768 ----
    const int i = (bid - (PREP_W_BLKS + PREP_AUG_BLKS)) * 1024 + tid * 4;
    *(f32x4*)(pot + i) = (f32x4){0.f, 0.f, 0.f, 0.f};
  }
}

// ---------------------------------------------------------------------------
// GEMM1 with fused gather via async DMA: compact row r of gene gb ->
// jid = rows_list[gb*NJC + r]; A row = concat(aug[don[jid]], aug[acc[jid]]).
// C = relu(A @ W1t^T + b1) stored bf16. Dynamic tile count via cnt[].
__global__ __launch_bounds__(256, 2) void gemm1_gather_kernel(
    const bf16* __restrict__ aug, const int* __restrict__ don,
    const int* __restrict__ acc, const int* __restrict__ rows_list,
    const int* __restrict__ cnt, const bf16* __restrict__ Bt,
    const float* __restrict__ bias, bf16* __restrict__ Cout) {
  __shared__ __align__(16) bf16 As[BM * BK];
  __shared__ __align__(16) bf16 Bs[BN * BK];
  const int tid = threadIdx.x;
  const int wave = tid >> 6;
  const int lane = tid & 63;
  int row_idx, col_idx;
  tile_from_bid(blockIdx.x, row_idx, col_idx);
  int gb;
  const int lt = map_tile(cnt, row_idx, gb);
  if (gb < 0) return;  // past the live tiles
  const int grow0 = gb * NJC + lt * BM;  // global compact row base
  const int col0 = col_idx * BN;
  const int wm = wave & 1;
  const int wn = wave >> 1;
  const int q = lane >> 4;
  const int rr = lane & 15;

  // staging descriptors: LDS slot L covers logical (row m, granule g)
  int mm[4], gg[4];
#pragma unroll
  for (int i = 0; i < 4; i++) {
    int L = wave * 256 + i * 64 + lane;
    int m = L >> 3;
    int g = (L & 7) ^ (m & 7);
    mm[i] = m; gg[i] = g;
  }

  // per-lane gathered A row base pointers (don half / acc half of K)
  const bf16* dp[4];
  const bf16* ap[4];
#pragma unroll
  for (int i = 0; i < 4; i++) {
    const int jid = rows_list[grow0 + mm[i]];
    dp[i] = aug + ((size_t)gb * NSA + don[gb * NJ + jid]) * NC;
    ap[i] = aug + ((size_t)gb * NSA + acc[gb * NJ + jid]) * NC;
  }

  f32x4 acc4[4][4] = {};

  for (int kt = 0; kt < KD / BK; ++kt) {
    const int ko = (kt & 7) * BK;  // offset within the 512-wide half
#pragma unroll
    for (int i = 0; i < 4; i++) {
      const bf16* abase = (kt < 8) ? dp[i] : ap[i];
      gload_lds16(abase + ko + gg[i] * 8,
                  As + (size_t)(wave * 256 + i * 64) * 8);
      gload_lds16(Bt + ((size_t)(col0 + mm[i]) * KD + kt * BK + gg[i] * 8),
                  Bs + (size_t)(wave * 256 + i * 64) * 8);
    }
    __syncthreads();
#pragma unroll
    for (int kk = 0; kk < 2; ++kk) {
      bf16x8 afr[4], bfr[4];
      const int g = kk * 4 + q;
#pragma unroll
      for (int mt = 0; mt < 4; mt++) {
        int m = wm * 64 + mt * 16 + rr;
        afr[mt] = *(const bf16x8*)(As + (m * 8 + (g ^ (m & 7))) * 8);
      }
#pragma unroll
      for (int nt = 0; nt < 4; nt++) {
        int n = wn * 64 + nt * 16 + rr;
        bfr[nt] = *(const bf16x8*)(Bs + (n * 8 + (g ^ (n & 7))) * 8);
      }
#pragma unroll
      for (int mt = 0; mt < 4; mt++)
#pragma unroll
        for (int nt = 0; nt < 4; nt++)
          acc4[mt][nt] = __builtin_amdgcn_mfma_f32_16x16x32_bf16(
              afr[mt], bfr[nt], acc4[mt][nt], 0, 0, 0);
    }
    __syncthreads();
  }

  // Epilogue. C/D layout: col = lane&15, row = quad*4 + reg
#pragma unroll
  for (int nt = 0; nt < 4; nt++) {
    const int col = col0 + wn * 64 + nt * 16 + rr;
    const float bv = bias[col];
#pragma unroll
    for (int mt = 0; mt < 4; mt++) {
      const int rbase = grow0 + wm * 64 + mt * 16 + q * 4;
#pragma unroll
      for (int rg = 0; rg < 4; rg++) {
        float v = fmaxf(acc4[mt][nt][rg] + bv, 0.f);
        Cout[(size_t)(rbase + rg) * KD + col] = __float2bfloat16(v);
      }
    }
  }
}

// ---------------------------------------------------------------------------
// GEMM2: pot contribution = relu(H1 @ W2t^T + b2) @ w3, atomicAdd per row.
__global__ __launch_bounds__(256, 2) void gemm2_kernel(
    const bf16* __restrict__ A, const int* __restrict__ cnt,
    const bf16* __restrict__ Bt, const float* __restrict__ bias,
    const float* __restrict__ w3, float* __restrict__ pot) {
  __shared__ __align__(16) bf16 As[BM * BK];
  __shared__ __align__(16) bf16 Bs[BN * BK];
  const int tid = threadIdx.x;
  const int wave = tid >> 6;
  const int lane = tid & 63;
  int row_idx, col_idx;
  tile_from_bid(blockIdx.x, row_idx, col_idx);
  int gb;
  const int lt = map_tile(cnt, row_idx, gb);
  if (gb < 0) return;
  const int grow0 = gb * NJC + lt * BM;
  const int col0 = col_idx * BN;
  const int wm = wave & 1;
  const int wn = wave >> 1;
  const int q = lane >> 4;
  const int rr = lane & 15;

  int mm[4], gg[4];
#pragma unroll
  for (int i = 0; i < 4; i++) {
    int L = wave * 256 + i * 64 + lane;
    int m = L >> 3;
    int g = (L & 7) ^ (m & 7);
    mm[i] = m; gg[i] = g;
  }

  f32x4 acc4[4][4] = {};

  for (int kt = 0; kt < KD / BK; ++kt) {
#pragma unroll
    for (int i = 0; i < 4; i++) {
      gload_lds16(A + ((size_t)(grow0 + mm[i]) * KD + kt * BK + gg[i] * 8),
                  As + (size_t)(wave * 256 + i * 64) * 8);
      gload_lds16(Bt + ((size_t)(col0 + mm[i]) * KD + kt * BK + gg[i] * 8),
                  Bs + (size_t)(wave * 256 + i * 64) * 8);
    }
    __syncthreads();
#pragma unroll
    for (int kk = 0; kk < 2; ++kk) {
      bf16x8 afr[4], bfr[4];
      const int g = kk * 4 + q;
#pragma unroll
      for (int mt = 0; mt < 4; mt++) {
        int m = wm * 64 + mt * 16 + rr;
        afr[mt] = *(const bf16x8*)(As + (m * 8 + (g ^ (m & 7))) * 8);
      }
#pragma unroll
      for (int nt = 0; nt < 4; nt++) {
        int n = wn * 64 + nt * 16 + rr;
        bfr[nt] = *(const bf16x8*)(Bs + (n * 8 + (g ^ (n & 7))) * 8);
      }
#pragma unroll
      for (int mt = 0; mt < 4; mt++)
#pragma unroll
        for (int nt = 0; nt < 4; nt++)
          acc4[mt][nt] = __builtin_amdgcn_mfma_f32_16x16x32_bf16(
              afr[mt], bfr[nt], acc4[mt][nt], 0, 0, 0);
    }
    __syncthreads();
  }

  float bv[4], wv[4];
#pragma unroll
  for (int nt = 0; nt < 4; nt++) {
    const int col = col0 + wn * 64 + nt * 16 + rr;
    bv[nt] = bias[col];
    wv[nt] = w3[col];
  }
#pragma unroll
  for (int mt = 0; mt < 4; mt++) {
#pragma unroll
    for (int rg = 0; rg < 4; rg++) {
      float s = 0.f;
#pragma unroll
      for (int nt = 0; nt < 4; nt++)
        s += fmaxf(acc4[mt][nt][rg] + bv[nt], 0.f) * wv[nt];
      s += __shfl_xor(s, 1);
      s += __shfl_xor(s, 2);
      s += __shfl_xor(s, 4);
      s += __shfl_xor(s, 8);
      if (rr == 0) {
        int row = grow0 + wm * 64 + mt * 16 + q * 4 + rg;
        atomicAdd(&pot[row], s);
      }
    }
  }
}

// ---------------------------------------------------------------------------
// Per-gene transcript potential sum + softmax over T+1 entries.
// pot is compact: junction j of gene b lives at pot[b*NJC + pmap[b*NJ + j]].
__global__ void transcript_softmax_kernel(const float* __restrict__ pot,
                                          const int* __restrict__ tj,
                                          const int* __restrict__ pmap,
                                          const float* __restrict__ b3,
                                          const float* __restrict__ refp,
                                          float* __restrict__ out) {
  const int b = blockIdx.x;
  const int t = threadIdx.x;  // 64 threads = 1 wave
  const int* tjb = tj + ((size_t)b * NT + t) * NKJ;
  const int* pm = pmap + (size_t)b * NJ;
  const float* pb = pot + (size_t)b * NJC;
  float s = 0.f;
#pragma unroll
  for (int k = 0; k < NKJ; k++) s += pb[pm[tjb[k]]];
  s += (float)NKJ * b3[0];
  const float ref = refp[0];
  float m = fmaxf(s, ref);
#pragma unroll
  for (int o = 1; o < 64; o <<= 1) m = fmaxf(m, __shfl_xor(m, o));
  const float e = expf(s - m);
  float denom = e;
#pragma unroll
  for (int o = 1; o < 64; o <<= 1) denom += __shfl_xor(denom, o);
  const float eref = expf(ref - m);
  denom += eref;
  out[b * (NT + 1) + t] = e / denom;
  if (t == 0) out[b * (NT + 1) + NT] = eref / denom;
}

// ---------------------------------------------------------------------------
extern "C" void kernel_launch(void* const* d_in, const int* in_sizes, int n_in,
                              void* d_out, int out_size, void* d_ws,
                              size_t ws_size, hipStream_t stream) {
  const float* ssr    = (const float*)d_in[0];   // [16,4096,512]
  const int*   don    = (const int*)d_in[1];     // [16,4096]
  const int*   acc    = (const int*)d_in[2];     // [16,4096]
  const int*   tj     = (const int*)d_in[3];     // [16,64,32]
  const float* W1     = (const float*)d_in[4];   // [1024,1024]
  const float* b1     = (const float*)d_in[5];   // [1024]
  const float* W2     = (const float*)d_in[6];   // [1024,1024]
  const float* b2     = (const float*)d_in[7];   // [1024]
  const float* W3     = (const float*)d_in[8];   // [1024,1]
  const float* b3     = (const float*)d_in[9];   // [1]
  const float* gstart = (const float*)d_in[10];  // [512]
  const float* gend   = (const float*)d_in[11];  // [512]
  const float* refp   = (const float*)d_in[12];  // [1]
  float* out = (float*)d_out;                    // [16,65]

  // workspace layout (~140 MiB)
  char* ws = (char*)d_ws;
  bf16* W1t = (bf16*)ws;                 ws += (size_t)KD * KD * 2;
  bf16* W2t = (bf16*)ws;                 ws += (size_t)KD * KD * 2;
  bf16* aug = (bf16*)ws;                 ws += (size_t)NB * NSA * NC * 2;
  bf16* H1  = (bf16*)ws;                 ws += (size_t)NMC * KD * 2;
  float* pot = (float*)ws;               ws += (size_t)NMC * 4;
  int* rows_list = (int*)ws;             ws += (size_t)NB * NJC * 4;
  int* pmap = (int*)ws;                  ws += (size_t)NB * NJ * 4;
  int* cnt = (int*)ws;                   ws += 64;
  unsigned char* sflag = (unsigned char*)ws;  ws += (size_t)NB * SFS;

  compact_kernel<<<NB, 1024, 0, stream>>>(tj, don, acc, rows_list, pmap, cnt,
                                          sflag);

  prep_kernel<<<PREP_W_BLKS + PREP_AUG_BLKS + PREP_POT_BLKS, 256, 0, stream>>>(
      W1, W1t, W2, W2t, ssr, gstart, gend, sflag, aug, pot);

  gemm1_gather_kernel<<<(NMC / BM) * (KD / BN), 256, 0, stream>>>(
      aug, don, acc, rows_list, cnt, W1t, b1, H1);

  gemm2_kernel<<<(NMC / BM) * (KD / BN), 256, 0, stream>>>(H1, cnt, W2t, b2,
                                                           W3, pot);

  transcript_softmax_kernel<<<NB, 64, 0, stream>>>(pot, tj, pmap, b3, refp,
                                                   out);
}